// Round 2
// baseline (231.017 us; speedup 1.0000x reference)
//
#include <hip/hip_runtime.h>
#include <hip/hip_bf16.h>
#include <cstddef>

typedef __bf16 bf16x8 __attribute__((ext_vector_type(8)));
typedef float f32x4 __attribute__((ext_vector_type(4)));
typedef float f32x16 __attribute__((ext_vector_type(16)));

// ---------------- prep kernels ----------------

// x fp32 NCHW [8,512,8,8] -> bf16 NHWC [8,8,8,512]
__global__ void convert_x_kernel(const float* __restrict__ x, __hip_bfloat16* __restrict__ act0) {
    int t = blockIdx.x * 256 + threadIdx.x;          // 262144 total
    int c = t & 511; int rest = t >> 9;
    int w = rest & 7; rest >>= 3; int h = rest & 7; int b = rest >> 3;
    act0[t] = __float2bfloat16(x[((b * 512 + c) * 8 + h) * 8 + w]);
}

// Weight transposes fused:
//   w1-w3: fp32 [CO][CI][3][3] -> bf16 [9][CO][CI]  (LDS-staged path)
//   w4,w5: fp32 [64][64][3][3] -> bf16 packed 32x32x16 B-fragment order
//          [tap][ks][nt][lane][8]: co = nt*32 + (lane&31), ci = ks*16 + (lane>>5)*8 + j
//   wf:    fp32 [3][64][3][3]  -> bf16 packed 16x16x32 [tap][ch][lane][8], co padded 3->16
__global__ void wtrans_all_kernel(const float* __restrict__ w1, __hip_bfloat16* __restrict__ o1,
                                  const float* __restrict__ w2, __hip_bfloat16* __restrict__ o2,
                                  const float* __restrict__ w3, __hip_bfloat16* __restrict__ o3,
                                  const float* __restrict__ w4, __hip_bfloat16* __restrict__ o4,
                                  const float* __restrict__ w5, __hip_bfloat16* __restrict__ o5,
                                  const float* __restrict__ wf, __hip_bfloat16* __restrict__ of) {
    int t = blockIdx.x * 256 + threadIdx.x;
    if (t >= 1631232) return;
    if (t < 1548288) {
        // [9][CO][CI] for stages 1-3
        const float* w; __hip_bfloat16* o; int lgci, lgco;
        if      (t < 1179648) { w = w1; o = o1; lgci = 9; lgco = 8; }
        else if (t < 1474560) { t -= 1179648; w = w2; o = o2; lgci = 8; lgco = 7; }
        else                  { t -= 1474560; w = w3; o = o3; lgci = 7; lgco = 6; }
        int CI = 1 << lgci;
        int ci = t & (CI - 1);
        int co = (t >> lgci) & ((1 << lgco) - 1);
        int tap = t >> (lgci + lgco);
        o[t] = __float2bfloat16(w[((size_t)co * CI + ci) * 9 + tap]);
    } else if (t < 1622016) {
        // packed 32x32x16 B-fragment layout for stages 4/5 (36864 elems each)
        const float* w; __hip_bfloat16* o;
        if (t < 1585152) { t -= 1548288; w = w4; o = o4; }
        else             { t -= 1585152; w = w5; o = o5; }
        int j  = t & 7;
        int ln = (t >> 3) & 63;
        int nt = (t >> 9) & 1;
        int ks = (t >> 10) & 3;
        int tap = t >> 12;
        int co = nt * 32 + (ln & 31);
        int ci = ks * 16 + (ln >> 5) * 8 + j;
        o[t] = __float2bfloat16(w[((size_t)co * 64 + ci) * 9 + tap]);
    } else {
        // packed final-conv 16x16x32 layout (9216 elems), co padded 3->16
        int u = t - 1622016;
        int j  = u & 7;
        int ln = (u >> 3) & 63;
        int ch = (u >> 9) & 1;
        int tap = u >> 10;
        int rr = ln & 15, qq = ln >> 4;
        int ci = ch * 32 + qq * 8 + j;
        float v = (rr < 3) ? wf[((size_t)rr * 64 + ci) * 9 + tap] : 0.f;
        of[u] = __float2bfloat16(v);
    }
}

// All style FCs fused. S laid out contiguously: S1@0 (8x256), S2@2048 (8x128),
// S3@3072, S4@3584, S5@4096 (8x64 each). One wave per (stage,b,o) -> 4608 waves.
__global__ void style_all_kernel(const float* __restrict__ style,
                                 const float* __restrict__ fw1, const float* __restrict__ fb1,
                                 const float* __restrict__ fw2, const float* __restrict__ fb2,
                                 const float* __restrict__ fw3, const float* __restrict__ fb3,
                                 const float* __restrict__ fw4, const float* __restrict__ fb4,
                                 const float* __restrict__ fw5, const float* __restrict__ fb5,
                                 float* __restrict__ S) {
    int wvid = blockIdx.x * 4 + (threadIdx.x >> 6);
    int lane = threadIdx.x & 63;
    const float* fw; const float* fb; int lg, sOff, local;
    if      (wvid < 2048) { fw = fw1; fb = fb1; lg = 8; sOff = 0;    local = wvid; }
    else if (wvid < 3072) { fw = fw2; fb = fb2; lg = 7; sOff = 2048; local = wvid - 2048; }
    else if (wvid < 3584) { fw = fw3; fb = fb3; lg = 6; sOff = 3072; local = wvid - 3072; }
    else if (wvid < 4096) { fw = fw4; fb = fb4; lg = 6; sOff = 3584; local = wvid - 3584; }
    else                  { fw = fw5; fb = fb5; lg = 6; sOff = 4096; local = wvid - 4096; }
    int b = local >> lg, o = local & ((1 << lg) - 1);
    const float* sb = style + b * 512;
    const float* fwo = fw + (size_t)o * 512;
    float p = 0.f;
    #pragma unroll
    for (int k = lane; k < 512; k += 64) p += sb[k] * fwo[k];
    #pragma unroll
    for (int off = 32; off > 0; off >>= 1) p += __shfl_down(p, off);
    if (lane == 0) S[sOff + local] = p + fb[o];
}

// ---------------- K-split partial conv (stages 1-3) ----------------
// 512 threads = 8 waves (2 waves/SIMD for latency hiding; was 4 waves = 1/SIMD).
// Each block: 16x16 output patch x 64 co x one 64-ci slice (blockIdx.z); fp32 partials.
template <int CI, int CO, int HS, int WS>
__launch_bounds__(512)
__global__ void conv_partial_kernel(const __hip_bfloat16* __restrict__ actIn,
                                    const __hip_bfloat16* __restrict__ wtr,
                                    float* __restrict__ Part) {
    constexpr int HO = HS * 2, WO = WS * 2;
    constexpr size_t sliceN = (size_t)8 * HO * WO * CO;
    const int tid = threadIdx.x;
    const int lane = tid & 63, wv = tid >> 6;       // wv in [0,8)
    const int r = lane & 15, q = lane >> 4;
    const int pw = WO / 16, ppb = (HO / 16) * pw;
    const int b = blockIdx.x / ppb;
    const int prest = blockIdx.x - b * ppb;
    const int ph = prest / pw, pwi = prest - ph * pw;
    const int oh0 = ph * 16, ow0 = pwi * 16;
    const int sh0 = oh0 >> 1, sw0 = ow0 >> 1;
    const int n0 = blockIdx.y * 64;
    const int ciOff = blockIdx.z * 64;

    __shared__ alignas(16) __hip_bfloat16 Tile[100 * 72];
    __shared__ alignas(16) __hip_bfloat16 Wlds[2][64 * 72];

    f32x4 acc[2][4];
    #pragma unroll
    for (int i = 0; i < 2; ++i)
        #pragma unroll
        for (int j = 0; j < 4; ++j) acc[i][j] = f32x4{0.f, 0.f, 0.f, 0.f};

    // stage A tile (100 px x 64 ci, padded stride 72)
    for (int i = tid; i < 800; i += 512) {
        int pix = i >> 3, koct = i & 7;
        int tr = pix / 10, tc2 = pix - tr * 10;
        int su = sh0 - 1 + tr, sv = sw0 - 1 + tc2;
        uint4 v = {0, 0, 0, 0};
        if (su >= 0 && su < HS && sv >= 0 && sv < WS)
            v = *(const uint4*)(actIn + ((size_t)((b * HS + su) * WS + sv) * CI + ciOff + koct * 8));
        *(uint4*)&Tile[pix * 72 + koct * 8] = v;
    }
    // stage tap-0 weights (512 entries, one per thread)
    {
        int co = tid >> 3, koct = tid & 7;
        *(uint4*)&Wlds[0][co * 72 + koct * 8] =
            *(const uint4*)(wtr + ((size_t)(n0 + co)) * CI + ciOff + koct * 8);
    }
    __syncthreads();

    #pragma unroll 1
    for (int tap = 0; tap < 9; ++tap) {
        const bool pf = (tap < 8);
        uint4 wr0 = {0,0,0,0};
        if (pf) {
            int co0 = tid >> 3, k0 = tid & 7;
            wr0 = *(const uint4*)(wtr + ((size_t)(tap + 1) * CO + n0 + co0) * CI + ciOff + k0 * 8);
        }
        const int dyv = tap / 3;
        const int dxm1 = tap - dyv * 3 - 1;
        const int tc = ((r + dxm1) >> 1) + 1;
        int apix[2];
        #pragma unroll
        for (int mt = 0; mt < 2; ++mt)
            apix[mt] = ((((wv * 2 + mt) + dyv - 1) >> 1) + 1) * 10 + tc;

        const int buf = tap & 1;
        #pragma unroll
        for (int ch = 0; ch < 2; ++ch) {
            bf16x8 af[2], bfr[4];
            #pragma unroll
            for (int mt = 0; mt < 2; ++mt)
                af[mt] = *(const bf16x8*)&Tile[apix[mt] * 72 + ch * 32 + q * 8];
            #pragma unroll
            for (int nt = 0; nt < 4; ++nt)
                bfr[nt] = *(const bf16x8*)&Wlds[buf][(nt * 16 + r) * 72 + ch * 32 + q * 8];
            #pragma unroll
            for (int mt = 0; mt < 2; ++mt)
                #pragma unroll
                for (int nt = 0; nt < 4; ++nt)
                    acc[mt][nt] = __builtin_amdgcn_mfma_f32_16x16x32_bf16(
                        af[mt], bfr[nt], acc[mt][nt], 0, 0, 0);
        }
        if (pf) {
            int nb = buf ^ 1;
            int co0 = tid >> 3, k0 = tid & 7;
            *(uint4*)&Wlds[nb][co0 * 72 + k0 * 8] = wr0;
            __syncthreads();
        }
    }

    // fp32 partial write, NHWC within slice
    float* P = Part + (size_t)blockIdx.z * sliceN;
    #pragma unroll
    for (int mt = 0; mt < 2; ++mt) {
        const int prow = wv * 2 + mt;
        #pragma unroll
        for (int t2 = 0; t2 < 4; ++t2) {
            const int pcol = q * 4 + t2;
            const size_t obase = ((size_t)(b * HO + oh0 + prow) * WO + ow0 + pcol) * CO + n0;
            #pragma unroll
            for (int nt = 0; nt < 4; ++nt)
                P[obase + nt * 16 + r] = acc[mt][nt][t2];
        }
    }
}

// sum KS fp32 partial slices -> scale + relu -> bf16 NHWC
template <int KS, int CO, int HW>
__launch_bounds__(256)
__global__ void reduce_kernel(const float* __restrict__ Part, const float* __restrict__ S,
                              __hip_bfloat16* __restrict__ actOut) {
    constexpr size_t sliceN = (size_t)8 * HW * CO;
    size_t e = ((size_t)blockIdx.x * 256 + threadIdx.x) * 4;
    if (e >= sliceN) return;
    f32x4 sum = {0.f, 0.f, 0.f, 0.f};
    #pragma unroll
    for (int k = 0; k < KS; ++k) sum += *(const f32x4*)(Part + (size_t)k * sliceN + e);
    const int co = (int)(e & (CO - 1));
    const int b = (int)(e / ((size_t)HW * CO));
    const float* Sb = S + b * CO + co;
    union { ushort4 u; __hip_bfloat16 h[4]; } pack;
    #pragma unroll
    for (int j = 0; j < 4; ++j)
        pack.h[j] = __float2bfloat16(fmaxf(sum[j] * Sb[j], 0.f));
    *(ushort4*)((unsigned short*)actOut + e) = pack.u;
}

// ---------------- fused conv, stages 4-5 (CI=CO=64), 32x32x16 MFMA ----------------
// B-fragments straight from global (L1/L2-resident packed weights), register
// double-buffered one tap ahead. A-tile staged to LDS ONCE; 9-tap loop has NO
// barriers and NO LDS writes. 32x32x16 = faster matrix pipe (2382 vs 2075 TF
// ceiling) and half the MFMA instruction count vs 16x16x32.
template <int HS, int WS>
__launch_bounds__(256)
__global__ void conv_patch_kernel(const __hip_bfloat16* __restrict__ actIn,
                                  const __hip_bfloat16* __restrict__ wpk,
                                  const float* __restrict__ S,
                                  __hip_bfloat16* __restrict__ actOut) {
    constexpr int HO = HS * 2, WO = WS * 2;

    const int tid = threadIdx.x;
    const int lane = tid & 63, wv = tid >> 6;
    const int r32 = lane & 31;           // A row / B col / D col
    const int ko  = lane >> 5;           // k-octet selector
    const int pcol = r32 & 15;           // px col within patch
    const int rsub = r32 >> 4;           // px row LSB within 32-row m-tile
    const int lane8 = lane * 8;

    const int pw = WO / 16, ppb = (HO / 16) * pw;
    const int b = blockIdx.x / ppb;
    const int prest = blockIdx.x - b * ppb;
    const int ph = prest / pw, pwi = prest - ph * pw;
    const int oh0 = ph * 16, ow0 = pwi * 16;
    const int sh0 = oh0 >> 1, sw0 = ow0 >> 1;

    __shared__ alignas(16) __hip_bfloat16 Tile[100 * 72];

    f32x16 acc[2][2];
    #pragma unroll
    for (int i = 0; i < 2; ++i)
        #pragma unroll
        for (int j = 0; j < 2; ++j)
            #pragma unroll
            for (int k = 0; k < 16; ++k) acc[i][j][k] = 0.f;

    const int wv4 = wv * 4;

    // stage source tile once (100 px x 64 ci, padded stride 72)
    for (int i = tid; i < 800; i += 256) {
        int pix = i >> 3, koct = i & 7;
        int tr = pix / 10, tc2 = pix - tr * 10;
        int su = sh0 - 1 + tr, sv = sw0 - 1 + tc2;
        uint4 v = {0, 0, 0, 0};
        if (su >= 0 && su < HS && sv >= 0 && sv < WS)
            v = *(const uint4*)(actIn + ((size_t)((b * HS + su) * WS + sv) * 64 + koct * 8));
        *(uint4*)&Tile[pix * 72 + koct * 8] = v;
    }
    __syncthreads();

    bf16x8 bA[4][2], bB[4][2];   // [ks][nt]

    auto loadB = [&](bf16x8 (&dst)[4][2], int tap) {
        #pragma unroll
        for (int ks = 0; ks < 4; ++ks)
            #pragma unroll
            for (int nt = 0; nt < 2; ++nt)
                dst[ks][nt] = *(const bf16x8*)(wpk + (((tap * 4 + ks) * 2 + nt) << 9) + lane8);
    };

    auto compute = [&](int tap, bf16x8 (&bfr)[4][2]) {
        const int dyv = tap / 3;
        const int dxm1 = tap - dyv * 3 - 1;
        const int tc = ((pcol + dxm1) >> 1) + 1;
        int apix[2];
        #pragma unroll
        for (int mt = 0; mt < 2; ++mt) {
            const int prow = wv4 + mt * 2 + rsub;
            apix[mt] = (((prow + dyv - 1) >> 1) + 1) * 10 + tc;
        }
        #pragma unroll
        for (int ks = 0; ks < 4; ++ks) {
            bf16x8 af[2];
            #pragma unroll
            for (int mt = 0; mt < 2; ++mt)
                af[mt] = *(const bf16x8*)&Tile[apix[mt] * 72 + ks * 16 + ko * 8];
            #pragma unroll
            for (int mt = 0; mt < 2; ++mt)
                #pragma unroll
                for (int nt = 0; nt < 2; ++nt)
                    acc[mt][nt] = __builtin_amdgcn_mfma_f32_32x32x16_bf16(
                        af[mt], bfr[ks][nt], acc[mt][nt], 0, 0, 0);
        }
    };

    loadB(bA, 0);
    #pragma unroll 1
    for (int it = 0; it < 4; ++it) {
        loadB(bB, 2 * it + 1);
        compute(2 * it, bA);
        loadB(bA, 2 * it + 2);          // taps 2,4,6,8
        compute(2 * it + 1, bB);
    }
    compute(8, bA);

    // D layout (32x32): col = lane&31 (co), row m = (reg&3)+8*(reg>>2)+4*(lane>>5)
    float sv_[2];
    #pragma unroll
    for (int nt = 0; nt < 2; ++nt) sv_[nt] = S[b * 64 + nt * 32 + r32];
    #pragma unroll
    for (int mt = 0; mt < 2; ++mt) {
        #pragma unroll
        for (int nt = 0; nt < 2; ++nt) {
            const int co = nt * 32 + r32;
            #pragma unroll
            for (int reg = 0; reg < 16; ++reg) {
                const int m = (reg & 3) + 8 * (reg >> 2) + 4 * ko;
                const int prow = wv4 + mt * 2 + (m >> 4);
                const int pc = m & 15;
                actOut[((size_t)(b * HO + oh0 + prow) * WO + ow0 + pc) * 64 + co] =
                    __float2bfloat16(fmaxf(acc[mt][nt][reg] * sv_[nt], 0.f));
            }
        }
    }
}

// ---------------- final conv: 64->3 at 256x256, +bias, fp32 NCHW out ----------------
// Weights (18 KB packed) direct from global; LDS holds only the activation tile.
__launch_bounds__(256)
__global__ void conv_final_kernel(const __hip_bfloat16* __restrict__ actIn, // [8][256][256][64]
                                  const __hip_bfloat16* __restrict__ wpkF, // packed [9][2][64][8]
                                  const float* __restrict__ bias,
                                  float* __restrict__ out) {               // [8][3][256][256]
    constexpr int HO = 256, WO = 256;
    const int tid = threadIdx.x, lane = tid & 63, wv = tid >> 6;
    const int r = lane & 15, q = lane >> 4;
    const int lane8 = lane * 8;

    const int ppb = 32 * 16;
    const int b = blockIdx.x / ppb;
    const int prest = blockIdx.x - b * ppb;
    const int ph = prest >> 4, pwi = prest & 15;
    const int oh0 = ph * 8, ow0 = pwi * 16;

    __shared__ alignas(16) __hip_bfloat16 Tile[10 * 18 * 72];

    for (int i = tid; i < 1440; i += 256) {
        int pix = i >> 3, koct = i & 7;
        int tr = pix / 18, tc2 = pix - tr * 18;
        int u = oh0 - 1 + tr, v = ow0 - 1 + tc2;
        uint4 val = {0, 0, 0, 0};
        if (u >= 0 && u < HO && v >= 0 && v < WO)
            val = *(const uint4*)(actIn + ((size_t)((b * HO + u) * WO + v) * 64 + koct * 8));
        *(uint4*)&Tile[pix * 72 + koct * 8] = val;
    }
    __syncthreads();

    f32x4 acc[2];
    acc[0] = f32x4{0.f, 0.f, 0.f, 0.f};
    acc[1] = f32x4{0.f, 0.f, 0.f, 0.f};

    #pragma unroll 1
    for (int tap = 0; tap < 9; ++tap) {
        const int dyv = tap / 3;
        const int dxv = tap - dyv * 3;
        const int tc = r + dxv;
        int apix[2];
        #pragma unroll
        for (int mt = 0; mt < 2; ++mt)
            apix[mt] = (wv * 2 + mt + dyv) * 18 + tc;
        #pragma unroll
        for (int ch = 0; ch < 2; ++ch) {
            bf16x8 bfr = *(const bf16x8*)(wpkF + ((tap * 2 + ch) << 9) + lane8);
            #pragma unroll
            for (int mt = 0; mt < 2; ++mt) {
                bf16x8 af = *(const bf16x8*)&Tile[apix[mt] * 72 + ch * 32 + q * 8];
                acc[mt] = __builtin_amdgcn_mfma_f32_16x16x32_bf16(af, bfr, acc[mt], 0, 0, 0);
            }
        }
    }

    if (r < 3) {
        const float bs = bias[r];
        #pragma unroll
        for (int mt = 0; mt < 2; ++mt) {
            const int prow = wv * 2 + mt;
            #pragma unroll
            for (int t2 = 0; t2 < 4; ++t2) {
                const int pcol = q * 4 + t2;
                out[((size_t)(b * 3 + r) << 16) + (oh0 + prow) * 256 + ow0 + pcol] =
                    acc[mt][t2] + bs;
            }
        }
    }
}

// ---------------- launch ----------------
extern "C" void kernel_launch(void* const* d_in, const int* in_sizes, int n_in,
                              void* d_out, int out_size, void* d_ws, size_t ws_size,
                              hipStream_t stream) {
    const float* x    = (const float*)d_in[0];
    const float* sty  = (const float*)d_in[1];
    const float* w1   = (const float*)d_in[2];
    const float* fw1  = (const float*)d_in[3];
    const float* fb1  = (const float*)d_in[4];
    const float* w2   = (const float*)d_in[5];
    const float* fw2  = (const float*)d_in[6];
    const float* fb2  = (const float*)d_in[7];
    const float* w3   = (const float*)d_in[8];
    const float* fw3  = (const float*)d_in[9];
    const float* fb3  = (const float*)d_in[10];
    const float* w4   = (const float*)d_in[11];
    const float* fw4  = (const float*)d_in[12];
    const float* fb4  = (const float*)d_in[13];
    const float* w5   = (const float*)d_in[14];
    const float* fw5  = (const float*)d_in[15];
    const float* fb5  = (const float*)d_in[16];
    const float* wf   = (const float*)d_in[17];
    const float* bf   = (const float*)d_in[18];
    float* out = (float*)d_out;

    char* ws = (char*)d_ws;
    size_t off = 0;
    auto alloc = [&](size_t bytes) {
        char* p = ws + off;
        off += (bytes + 255) & ~(size_t)255;
        return p;
    };
    // S1..S5 contiguous (all sizes multiples of 256 B) -> fused style kernel writes S1 base
    float* S1 = (float*)alloc(8 * 256 * 4);
    float* S2 = (float*)alloc(8 * 128 * 4);
    float* S3 = (float*)alloc(8 * 64 * 4);
    float* S4 = (float*)alloc(8 * 64 * 4);
    float* S5 = (float*)alloc(8 * 64 * 4);
    __hip_bfloat16* act0 = (__hip_bfloat16*)alloc((size_t)262144 * 2);   // 8x8x8x512
    __hip_bfloat16* act1 = (__hip_bfloat16*)alloc((size_t)524288 * 2);   // 8x16x16x256
    __hip_bfloat16* act2 = (__hip_bfloat16*)alloc((size_t)1048576 * 2);  // 8x32x32x128
    __hip_bfloat16* act3 = (__hip_bfloat16*)alloc((size_t)2097152 * 2);  // 8x64x64x64
    __hip_bfloat16* act4 = (__hip_bfloat16*)alloc((size_t)8388608 * 2);  // 8x128x128x64
    __hip_bfloat16* act5 = (__hip_bfloat16*)alloc((size_t)33554432 * 2); // 8x256x256x64
    __hip_bfloat16* wt1  = (__hip_bfloat16*)alloc((size_t)9 * 256 * 512 * 2);
    __hip_bfloat16* wt2  = (__hip_bfloat16*)alloc((size_t)9 * 128 * 256 * 2);
    __hip_bfloat16* wt3  = (__hip_bfloat16*)alloc((size_t)9 * 64 * 128 * 2);
    __hip_bfloat16* wt4  = (__hip_bfloat16*)alloc((size_t)9 * 64 * 64 * 2);   // packed 32x32
    __hip_bfloat16* wt5  = (__hip_bfloat16*)alloc((size_t)9 * 64 * 64 * 2);   // packed 32x32
    __hip_bfloat16* wtF  = (__hip_bfloat16*)alloc((size_t)9 * 16 * 64 * 2);   // packed 16x16
    if (off > ws_size) return;

    // fp32 K-split partial scratch (16 MB) aliased onto act5 (64 MB, written only by
    // stage 5 which runs after the last reduce) -- no extra ws footprint.
    float* Part = (float*)act5;

    convert_x_kernel<<<1024, 256, 0, stream>>>(x, act0);
    wtrans_all_kernel<<<6372, 256, 0, stream>>>(w1, wt1, w2, wt2, w3, wt3,
                                                w4, wt4, w5, wt5, wf, wtF);
    style_all_kernel<<<1152, 256, 0, stream>>>(sty, fw1, fb1, fw2, fb2, fw3, fb3,
                                               fw4, fb4, fw5, fb5, S1);

    // stages 1-3: K-split partials (256 blocks x 512 threads each) + reduce
    conv_partial_kernel<512, 256, 8, 8><<<dim3(8, 4, 8), 512, 0, stream>>>(act0, wt1, Part);
    reduce_kernel<8, 256, 256><<<512, 256, 0, stream>>>(Part, S1, act1);
    conv_partial_kernel<256, 128, 16, 16><<<dim3(32, 2, 4), 512, 0, stream>>>(act1, wt2, Part);
    reduce_kernel<4, 128, 1024><<<1024, 256, 0, stream>>>(Part, S2, act2);
    conv_partial_kernel<128, 64, 32, 32><<<dim3(128, 1, 2), 512, 0, stream>>>(act2, wt3, Part);
    reduce_kernel<2, 64, 4096><<<2048, 256, 0, stream>>>(Part, S3, act3);

    // stages 4-5: barrier-free fused patch kernel, 32x32x16 MFMA, B direct from global
    conv_patch_kernel<64, 64><<<dim3(512), 256, 0, stream>>>(act3, wt4, S4, act4);
    conv_patch_kernel<128, 128><<<dim3(2048), 256, 0, stream>>>(act4, wt5, S5, act5);
    conv_final_kernel<<<4096, 256, 0, stream>>>(act5, wtF, bf, out);
}

// Round 4
// 229.105 us; speedup vs baseline: 1.0083x; 1.0083x over previous
//
#include <hip/hip_runtime.h>
#include <hip/hip_bf16.h>
#include <cstddef>

typedef __bf16 bf16x8 __attribute__((ext_vector_type(8)));
typedef float f32x4 __attribute__((ext_vector_type(4)));

// ---------------- prep kernels ----------------

// x fp32 NCHW [8,512,8,8] -> bf16 NHWC [8,8,8,512]
__global__ void convert_x_kernel(const float* __restrict__ x, __hip_bfloat16* __restrict__ act0) {
    int t = blockIdx.x * 256 + threadIdx.x;          // 262144 total
    int c = t & 511; int rest = t >> 9;
    int w = rest & 7; rest >>= 3; int h = rest & 7; int b = rest >> 3;
    act0[t] = __float2bfloat16(x[((b * 512 + c) * 8 + h) * 8 + w]);
}

// Weight transposes fused:
//   w1-w3: fp32 [CO][CI][3][3] -> bf16 [9][CO][CI]  (LDS-staged path)
//   w4,w5: fp32 [64][64][3][3] -> bf16 packed 16x16x32 B-fragment order
//          [tap][nt][ch][lane][8]: co = nt*16 + (lane&15), ci = ch*32 + (lane>>4)*8 + j
//   wf:    fp32 [3][64][3][3]  -> bf16 packed 16x16x32 [tap][ch][lane][8], co padded 3->16
__global__ void wtrans_all_kernel(const float* __restrict__ w1, __hip_bfloat16* __restrict__ o1,
                                  const float* __restrict__ w2, __hip_bfloat16* __restrict__ o2,
                                  const float* __restrict__ w3, __hip_bfloat16* __restrict__ o3,
                                  const float* __restrict__ w4, __hip_bfloat16* __restrict__ o4,
                                  const float* __restrict__ w5, __hip_bfloat16* __restrict__ o5,
                                  const float* __restrict__ wf, __hip_bfloat16* __restrict__ of) {
    int t = blockIdx.x * 256 + threadIdx.x;
    if (t >= 1631232) return;
    if (t < 1548288) {
        // [9][CO][CI] for stages 1-3
        const float* w; __hip_bfloat16* o; int lgci, lgco;
        if      (t < 1179648) { w = w1; o = o1; lgci = 9; lgco = 8; }
        else if (t < 1474560) { t -= 1179648; w = w2; o = o2; lgci = 8; lgco = 7; }
        else                  { t -= 1474560; w = w3; o = o3; lgci = 7; lgco = 6; }
        int CI = 1 << lgci;
        int ci = t & (CI - 1);
        int co = (t >> lgci) & ((1 << lgco) - 1);
        int tap = t >> (lgci + lgco);
        o[t] = __float2bfloat16(w[((size_t)co * CI + ci) * 9 + tap]);
    } else if (t < 1622016) {
        // packed 16x16x32 B-fragment layout for stages 4/5 (36864 elems each)
        const float* w; __hip_bfloat16* o;
        if (t < 1585152) { t -= 1548288; w = w4; o = o4; }
        else             { t -= 1585152; w = w5; o = o5; }
        int j  = t & 7;
        int ln = (t >> 3) & 63;
        int ch = (t >> 9) & 1;
        int nt = (t >> 10) & 3;
        int tap = t >> 12;
        int rr = ln & 15, qq = ln >> 4;
        int co = nt * 16 + rr;
        int ci = ch * 32 + qq * 8 + j;
        o[t] = __float2bfloat16(w[((size_t)co * 64 + ci) * 9 + tap]);
    } else {
        // packed final-conv 16x16x32 layout (9216 elems), co padded 3->16
        int u = t - 1622016;
        int j  = u & 7;
        int ln = (u >> 3) & 63;
        int ch = (u >> 9) & 1;
        int tap = u >> 10;
        int rr = ln & 15, qq = ln >> 4;
        int ci = ch * 32 + qq * 8 + j;
        float v = (rr < 3) ? wf[((size_t)rr * 64 + ci) * 9 + tap] : 0.f;
        of[u] = __float2bfloat16(v);
    }
}

// All style FCs fused. S laid out contiguously: S1@0 (8x256), S2@2048 (8x128),
// S3@3072, S4@3584, S5@4096 (8x64 each). One wave per (stage,b,o) -> 4608 waves.
__global__ void style_all_kernel(const float* __restrict__ style,
                                 const float* __restrict__ fw1, const float* __restrict__ fb1,
                                 const float* __restrict__ fw2, const float* __restrict__ fb2,
                                 const float* __restrict__ fw3, const float* __restrict__ fb3,
                                 const float* __restrict__ fw4, const float* __restrict__ fb4,
                                 const float* __restrict__ fw5, const float* __restrict__ fb5,
                                 float* __restrict__ S) {
    int wvid = blockIdx.x * 4 + (threadIdx.x >> 6);
    int lane = threadIdx.x & 63;
    const float* fw; const float* fb; int lg, sOff, local;
    if      (wvid < 2048) { fw = fw1; fb = fb1; lg = 8; sOff = 0;    local = wvid; }
    else if (wvid < 3072) { fw = fw2; fb = fb2; lg = 7; sOff = 2048; local = wvid - 2048; }
    else if (wvid < 3584) { fw = fw3; fb = fb3; lg = 6; sOff = 3072; local = wvid - 3072; }
    else if (wvid < 4096) { fw = fw4; fb = fb4; lg = 6; sOff = 3584; local = wvid - 3584; }
    else                  { fw = fw5; fb = fb5; lg = 6; sOff = 4096; local = wvid - 4096; }
    int b = local >> lg, o = local & ((1 << lg) - 1);
    const float* sb = style + b * 512;
    const float* fwo = fw + (size_t)o * 512;
    float p = 0.f;
    #pragma unroll
    for (int k = lane; k < 512; k += 64) p += sb[k] * fwo[k];
    #pragma unroll
    for (int off = 32; off > 0; off >>= 1) p += __shfl_down(p, off);
    if (lane == 0) S[sOff + local] = p + fb[o];
}

// ---------------- K-split partial conv (stages 1-3) ----------------
// 512 threads = 8 waves (2 waves/SIMD). Each block: 16x16 output patch x 64 co x
// one 64-ci slice (blockIdx.z); fp32 partials.
template <int CI, int CO, int HS, int WS>
__launch_bounds__(512)
__global__ void conv_partial_kernel(const __hip_bfloat16* __restrict__ actIn,
                                    const __hip_bfloat16* __restrict__ wtr,
                                    float* __restrict__ Part) {
    constexpr int HO = HS * 2, WO = WS * 2;
    constexpr size_t sliceN = (size_t)8 * HO * WO * CO;
    const int tid = threadIdx.x;
    const int lane = tid & 63, wv = tid >> 6;       // wv in [0,8)
    const int r = lane & 15, q = lane >> 4;
    const int pw = WO / 16, ppb = (HO / 16) * pw;
    const int b = blockIdx.x / ppb;
    const int prest = blockIdx.x - b * ppb;
    const int ph = prest / pw, pwi = prest - ph * pw;
    const int oh0 = ph * 16, ow0 = pwi * 16;
    const int sh0 = oh0 >> 1, sw0 = ow0 >> 1;
    const int n0 = blockIdx.y * 64;
    const int ciOff = blockIdx.z * 64;

    __shared__ alignas(16) __hip_bfloat16 Tile[100 * 72];
    __shared__ alignas(16) __hip_bfloat16 Wlds[2][64 * 72];

    f32x4 acc[2][4];
    #pragma unroll
    for (int i = 0; i < 2; ++i)
        #pragma unroll
        for (int j = 0; j < 4; ++j) acc[i][j] = f32x4{0.f, 0.f, 0.f, 0.f};

    // stage A tile (100 px x 64 ci, padded stride 72)
    for (int i = tid; i < 800; i += 512) {
        int pix = i >> 3, koct = i & 7;
        int tr = pix / 10, tc2 = pix - tr * 10;
        int su = sh0 - 1 + tr, sv = sw0 - 1 + tc2;
        uint4 v = {0, 0, 0, 0};
        if (su >= 0 && su < HS && sv >= 0 && sv < WS)
            v = *(const uint4*)(actIn + ((size_t)((b * HS + su) * WS + sv) * CI + ciOff + koct * 8));
        *(uint4*)&Tile[pix * 72 + koct * 8] = v;
    }
    // stage tap-0 weights (512 entries, one per thread)
    {
        int co = tid >> 3, koct = tid & 7;
        *(uint4*)&Wlds[0][co * 72 + koct * 8] =
            *(const uint4*)(wtr + ((size_t)(n0 + co)) * CI + ciOff + koct * 8);
    }
    __syncthreads();

    #pragma unroll 1
    for (int tap = 0; tap < 9; ++tap) {
        const bool pf = (tap < 8);
        uint4 wr0 = {0,0,0,0};
        if (pf) {
            int co0 = tid >> 3, k0 = tid & 7;
            wr0 = *(const uint4*)(wtr + ((size_t)(tap + 1) * CO + n0 + co0) * CI + ciOff + k0 * 8);
        }
        const int dyv = tap / 3;
        const int dxm1 = tap - dyv * 3 - 1;
        const int tc = ((r + dxm1) >> 1) + 1;
        int apix[2];
        #pragma unroll
        for (int mt = 0; mt < 2; ++mt)
            apix[mt] = ((((wv * 2 + mt) + dyv - 1) >> 1) + 1) * 10 + tc;

        const int buf = tap & 1;
        #pragma unroll
        for (int ch = 0; ch < 2; ++ch) {
            bf16x8 af[2], bfr[4];
            #pragma unroll
            for (int mt = 0; mt < 2; ++mt)
                af[mt] = *(const bf16x8*)&Tile[apix[mt] * 72 + ch * 32 + q * 8];
            #pragma unroll
            for (int nt = 0; nt < 4; ++nt)
                bfr[nt] = *(const bf16x8*)&Wlds[buf][(nt * 16 + r) * 72 + ch * 32 + q * 8];
            #pragma unroll
            for (int mt = 0; mt < 2; ++mt)
                #pragma unroll
                for (int nt = 0; nt < 4; ++nt)
                    acc[mt][nt] = __builtin_amdgcn_mfma_f32_16x16x32_bf16(
                        af[mt], bfr[nt], acc[mt][nt], 0, 0, 0);
        }
        if (pf) {
            int nb = buf ^ 1;
            int co0 = tid >> 3, k0 = tid & 7;
            *(uint4*)&Wlds[nb][co0 * 72 + k0 * 8] = wr0;
            __syncthreads();
        }
    }

    // fp32 partial write, NHWC within slice
    float* P = Part + (size_t)blockIdx.z * sliceN;
    #pragma unroll
    for (int mt = 0; mt < 2; ++mt) {
        const int prow = wv * 2 + mt;
        #pragma unroll
        for (int t2 = 0; t2 < 4; ++t2) {
            const int pcol = q * 4 + t2;
            const size_t obase = ((size_t)(b * HO + oh0 + prow) * WO + ow0 + pcol) * CO + n0;
            #pragma unroll
            for (int nt = 0; nt < 4; ++nt)
                P[obase + nt * 16 + r] = acc[mt][nt][t2];
        }
    }
}

// sum KS fp32 partial slices -> scale + relu -> bf16 NHWC
template <int KS, int CO, int HW>
__launch_bounds__(256)
__global__ void reduce_kernel(const float* __restrict__ Part, const float* __restrict__ S,
                              __hip_bfloat16* __restrict__ actOut) {
    constexpr size_t sliceN = (size_t)8 * HW * CO;
    size_t e = ((size_t)blockIdx.x * 256 + threadIdx.x) * 4;
    if (e >= sliceN) return;
    f32x4 sum = {0.f, 0.f, 0.f, 0.f};
    #pragma unroll
    for (int k = 0; k < KS; ++k) sum += *(const f32x4*)(Part + (size_t)k * sliceN + e);
    const int co = (int)(e & (CO - 1));
    const int b = (int)(e / ((size_t)HW * CO));
    const float* Sb = S + b * CO + co;
    union { ushort4 u; __hip_bfloat16 h[4]; } pack;
    #pragma unroll
    for (int j = 0; j < 4; ++j)
        pack.h[j] = __float2bfloat16(fmaxf(sum[j] * Sb[j], 0.f));
    *(ushort4*)((unsigned short*)actOut + e) = pack.u;
}

// ---------------- fused conv, stages 4-5 (CI=CO=64), CO-split for occupancy ----------
// Each block: 16x16 output patch x 32 co (blockIdx.y selects co half). B-fragments
// straight from global (L1-resident now: 36 KB/block), register double-buffered one
// tap ahead. A-tile staged to LDS ONCE; 9-tap loop has NO barriers and NO LDS writes.
// Per-wave regs ~110 (acc 32 + Bdbuf 32) -> 4 waves/SIMD vs 2 before.
template <int HS, int WS>
__launch_bounds__(256)
__global__ void conv_patch_kernel(const __hip_bfloat16* __restrict__ actIn,
                                  const __hip_bfloat16* __restrict__ wpk,
                                  const float* __restrict__ S,
                                  __hip_bfloat16* __restrict__ actOut) {
    constexpr int HO = HS * 2, WO = WS * 2;

    const int tid = threadIdx.x;
    const int lane = tid & 63, wv = tid >> 6;
    const int r = lane & 15, q = lane >> 4;
    const int lane8 = lane * 8;

    const int pw = WO / 16, ppb = (HO / 16) * pw;
    const int b = blockIdx.x / ppb;
    const int prest = blockIdx.x - b * ppb;
    const int ph = prest / pw, pwi = prest - ph * pw;
    const int oh0 = ph * 16, ow0 = pwi * 16;
    const int sh0 = oh0 >> 1, sw0 = ow0 >> 1;
    const int by = blockIdx.y;          // co half: co in [by*32, by*32+32)
    const int n0 = by * 32;

    __shared__ alignas(16) __hip_bfloat16 Tile[100 * 72];

    f32x4 acc[4][2];
    #pragma unroll
    for (int i = 0; i < 4; ++i)
        #pragma unroll
        for (int j = 0; j < 2; ++j) acc[i][j] = f32x4{0.f, 0.f, 0.f, 0.f};

    const int wv4 = wv * 4;

    // stage source tile once (100 px x 64 ci, padded stride 72)
    for (int i = tid; i < 800; i += 256) {
        int pix = i >> 3, koct = i & 7;
        int tr = pix / 10, tc2 = pix - tr * 10;
        int su = sh0 - 1 + tr, sv = sw0 - 1 + tc2;
        uint4 v = {0, 0, 0, 0};
        if (su >= 0 && su < HS && sv >= 0 && sv < WS)
            v = *(const uint4*)(actIn + ((size_t)((b * HS + su) * WS + sv) * 64 + koct * 8));
        *(uint4*)&Tile[pix * 72 + koct * 8] = v;
    }
    __syncthreads();

    bf16x8 bA[2][2], bB[2][2];   // [nt][ch], nt covers this block's 2 co-16-tiles

    auto loadB = [&](bf16x8 (&dst)[2][2], int tap) {
        #pragma unroll
        for (int nt = 0; nt < 2; ++nt)
            #pragma unroll
            for (int ch = 0; ch < 2; ++ch)
                dst[nt][ch] = *(const bf16x8*)(
                    wpk + ((tap * 8 + (by * 2 + nt) * 2 + ch) << 9) + lane8);
    };

    auto compute = [&](int tap, bf16x8 (&bfr)[2][2]) {
        const int dyv = tap / 3;
        const int dxm1 = tap - dyv * 3 - 1;
        const int tc = ((r + dxm1) >> 1) + 1;
        int apix[4];
        #pragma unroll
        for (int mt = 0; mt < 4; ++mt)
            apix[mt] = ((((wv4 + mt) + dyv - 1) >> 1) + 1) * 10 + tc;
        #pragma unroll
        for (int ch = 0; ch < 2; ++ch) {
            bf16x8 af[4];
            #pragma unroll
            for (int mt = 0; mt < 4; ++mt)
                af[mt] = *(const bf16x8*)&Tile[apix[mt] * 72 + ch * 32 + q * 8];
            #pragma unroll
            for (int mt = 0; mt < 4; ++mt)
                #pragma unroll
                for (int nt = 0; nt < 2; ++nt)
                    acc[mt][nt] = __builtin_amdgcn_mfma_f32_16x16x32_bf16(
                        af[mt], bfr[nt][ch], acc[mt][nt], 0, 0, 0);
        }
    };

    loadB(bA, 0);
    #pragma unroll 1
    for (int it = 0; it < 4; ++it) {
        loadB(bB, 2 * it + 1);
        compute(2 * it, bA);
        loadB(bA, 2 * it + 2);          // taps 2,4,6,8
        compute(2 * it + 1, bB);
    }
    compute(8, bA);

    float sv_[2];
    #pragma unroll
    for (int nt = 0; nt < 2; ++nt) sv_[nt] = S[b * 64 + n0 + nt * 16 + r];
    #pragma unroll
    for (int mt = 0; mt < 4; ++mt) {
        const int prow = wv4 + mt;
        #pragma unroll
        for (int t2 = 0; t2 < 4; ++t2) {
            const int pcol = q * 4 + t2;
            const size_t obase = ((size_t)(b * HO + oh0 + prow) * WO + ow0 + pcol) * 64 + n0;
            #pragma unroll
            for (int nt = 0; nt < 2; ++nt)
                actOut[obase + nt * 16 + r] =
                    __float2bfloat16(fmaxf(acc[mt][nt][t2] * sv_[nt], 0.f));
        }
    }
}

// ---------------- final conv: 64->3 at 256x256, +bias, fp32 NCHW out ----------------
// Weights (18 KB packed) direct from global; LDS holds only the activation tile.
__launch_bounds__(256)
__global__ void conv_final_kernel(const __hip_bfloat16* __restrict__ actIn, // [8][256][256][64]
                                  const __hip_bfloat16* __restrict__ wpkF, // packed [9][2][64][8]
                                  const float* __restrict__ bias,
                                  float* __restrict__ out) {               // [8][3][256][256]
    constexpr int HO = 256, WO = 256;
    const int tid = threadIdx.x, lane = tid & 63, wv = tid >> 6;
    const int r = lane & 15, q = lane >> 4;
    const int lane8 = lane * 8;

    const int ppb = 32 * 16;
    const int b = blockIdx.x / ppb;
    const int prest = blockIdx.x - b * ppb;
    const int ph = prest >> 4, pwi = prest & 15;
    const int oh0 = ph * 8, ow0 = pwi * 16;

    __shared__ alignas(16) __hip_bfloat16 Tile[10 * 18 * 72];

    for (int i = tid; i < 1440; i += 256) {
        int pix = i >> 3, koct = i & 7;
        int tr = pix / 18, tc2 = pix - tr * 18;
        int u = oh0 - 1 + tr, v = ow0 - 1 + tc2;
        uint4 val = {0, 0, 0, 0};
        if (u >= 0 && u < HO && v >= 0 && v < WO)
            val = *(const uint4*)(actIn + ((size_t)((b * HO + u) * WO + v) * 64 + koct * 8));
        *(uint4*)&Tile[pix * 72 + koct * 8] = val;
    }
    __syncthreads();

    f32x4 acc[2];
    acc[0] = f32x4{0.f, 0.f, 0.f, 0.f};
    acc[1] = f32x4{0.f, 0.f, 0.f, 0.f};

    #pragma unroll 1
    for (int tap = 0; tap < 9; ++tap) {
        const int dyv = tap / 3;
        const int dxv = tap - dyv * 3;
        const int tc = r + dxv;
        int apix[2];
        #pragma unroll
        for (int mt = 0; mt < 2; ++mt)
            apix[mt] = (wv * 2 + mt + dyv) * 18 + tc;
        #pragma unroll
        for (int ch = 0; ch < 2; ++ch) {
            bf16x8 bfr = *(const bf16x8*)(wpkF + ((tap * 2 + ch) << 9) + lane8);
            #pragma unroll
            for (int mt = 0; mt < 2; ++mt) {
                bf16x8 af = *(const bf16x8*)&Tile[apix[mt] * 72 + ch * 32 + q * 8];
                acc[mt] = __builtin_amdgcn_mfma_f32_16x16x32_bf16(af, bfr, acc[mt], 0, 0, 0);
            }
        }
    }

    if (r < 3) {
        const float bs = bias[r];
        #pragma unroll
        for (int mt = 0; mt < 2; ++mt) {
            const int prow = wv * 2 + mt;
            #pragma unroll
            for (int t2 = 0; t2 < 4; ++t2) {
                const int pcol = q * 4 + t2;
                out[((size_t)(b * 3 + r) << 16) + (oh0 + prow) * 256 + ow0 + pcol] =
                    acc[mt][t2] + bs;
            }
        }
    }
}

// ---------------- launch ----------------
extern "C" void kernel_launch(void* const* d_in, const int* in_sizes, int n_in,
                              void* d_out, int out_size, void* d_ws, size_t ws_size,
                              hipStream_t stream) {
    const float* x    = (const float*)d_in[0];
    const float* sty  = (const float*)d_in[1];
    const float* w1   = (const float*)d_in[2];
    const float* fw1  = (const float*)d_in[3];
    const float* fb1  = (const float*)d_in[4];
    const float* w2   = (const float*)d_in[5];
    const float* fw2  = (const float*)d_in[6];
    const float* fb2  = (const float*)d_in[7];
    const float* w3   = (const float*)d_in[8];
    const float* fw3  = (const float*)d_in[9];
    const float* fb3  = (const float*)d_in[10];
    const float* w4   = (const float*)d_in[11];
    const float* fw4  = (const float*)d_in[12];
    const float* fb4  = (const float*)d_in[13];
    const float* w5   = (const float*)d_in[14];
    const float* fw5  = (const float*)d_in[15];
    const float* fb5  = (const float*)d_in[16];
    const float* wf   = (const float*)d_in[17];
    const float* bf   = (const float*)d_in[18];
    float* out = (float*)d_out;

    char* ws = (char*)d_ws;
    size_t off = 0;
    auto alloc = [&](size_t bytes) {
        char* p = ws + off;
        off += (bytes + 255) & ~(size_t)255;
        return p;
    };
    // S1..S5 contiguous (all sizes multiples of 256 B) -> fused style kernel writes S1 base
    float* S1 = (float*)alloc(8 * 256 * 4);
    float* S2 = (float*)alloc(8 * 128 * 4);
    float* S3 = (float*)alloc(8 * 64 * 4);
    float* S4 = (float*)alloc(8 * 64 * 4);
    float* S5 = (float*)alloc(8 * 64 * 4);
    __hip_bfloat16* act0 = (__hip_bfloat16*)alloc((size_t)262144 * 2);   // 8x8x8x512
    __hip_bfloat16* act1 = (__hip_bfloat16*)alloc((size_t)524288 * 2);   // 8x16x16x256
    __hip_bfloat16* act2 = (__hip_bfloat16*)alloc((size_t)1048576 * 2);  // 8x32x32x128
    __hip_bfloat16* act3 = (__hip_bfloat16*)alloc((size_t)2097152 * 2);  // 8x64x64x64
    __hip_bfloat16* act4 = (__hip_bfloat16*)alloc((size_t)8388608 * 2);  // 8x128x128x64
    __hip_bfloat16* act5 = (__hip_bfloat16*)alloc((size_t)33554432 * 2); // 8x256x256x64
    __hip_bfloat16* wt1  = (__hip_bfloat16*)alloc((size_t)9 * 256 * 512 * 2);
    __hip_bfloat16* wt2  = (__hip_bfloat16*)alloc((size_t)9 * 128 * 256 * 2);
    __hip_bfloat16* wt3  = (__hip_bfloat16*)alloc((size_t)9 * 64 * 128 * 2);
    __hip_bfloat16* wt4  = (__hip_bfloat16*)alloc((size_t)9 * 64 * 64 * 2);   // packed 16x16
    __hip_bfloat16* wt5  = (__hip_bfloat16*)alloc((size_t)9 * 64 * 64 * 2);   // packed 16x16
    __hip_bfloat16* wtF  = (__hip_bfloat16*)alloc((size_t)9 * 16 * 64 * 2);   // packed 16x16
    if (off > ws_size) return;

    // fp32 K-split partial scratch (16 MB) aliased onto act5 (64 MB, written only by
    // stage 5 which runs after the last reduce) -- no extra ws footprint.
    float* Part = (float*)act5;

    convert_x_kernel<<<1024, 256, 0, stream>>>(x, act0);
    wtrans_all_kernel<<<6372, 256, 0, stream>>>(w1, wt1, w2, wt2, w3, wt3,
                                                w4, wt4, w5, wt5, wf, wtF);
    style_all_kernel<<<1152, 256, 0, stream>>>(sty, fw1, fb1, fw2, fb2, fw3, fb3,
                                               fw4, fb4, fw5, fb5, S1);

    // stages 1-3: K-split partials (256 blocks x 512 threads each) + reduce
    conv_partial_kernel<512, 256, 8, 8><<<dim3(8, 4, 8), 512, 0, stream>>>(act0, wt1, Part);
    reduce_kernel<8, 256, 256><<<512, 256, 0, stream>>>(Part, S1, act1);
    conv_partial_kernel<256, 128, 16, 16><<<dim3(32, 2, 4), 512, 0, stream>>>(act1, wt2, Part);
    reduce_kernel<4, 128, 1024><<<1024, 256, 0, stream>>>(Part, S2, act2);
    conv_partial_kernel<128, 64, 32, 32><<<dim3(128, 1, 2), 512, 0, stream>>>(act2, wt3, Part);
    reduce_kernel<2, 64, 4096><<<2048, 256, 0, stream>>>(Part, S3, act3);

    // stages 4-5: barrier-free fused patch kernel, CO-split (blockIdx.y) for occupancy
    conv_patch_kernel<64, 64><<<dim3(512, 2), 256, 0, stream>>>(act3, wt4, S4, act4);
    conv_patch_kernel<128, 128><<<dim3(2048, 2), 256, 0, stream>>>(act4, wt5, S5, act5);
    conv_final_kernel<<<4096, 256, 0, stream>>>(act5, wtF, bf, out);
}

// Round 5
// 217.444 us; speedup vs baseline: 1.0624x; 1.0536x over previous
//
#include <hip/hip_runtime.h>
#include <hip/hip_bf16.h>
#include <cstddef>

typedef __bf16 bf16x8 __attribute__((ext_vector_type(8)));
typedef float f32x4 __attribute__((ext_vector_type(4)));

// ---------------- prep kernels ----------------

// x fp32 NCHW [8,512,8,8] -> bf16 NHWC [8,8,8,512]
__global__ void convert_x_kernel(const float* __restrict__ x, __hip_bfloat16* __restrict__ act0) {
    int t = blockIdx.x * 256 + threadIdx.x;          // 262144 total
    int c = t & 511; int rest = t >> 9;
    int w = rest & 7; rest >>= 3; int h = rest & 7; int b = rest >> 3;
    act0[t] = __float2bfloat16(x[((b * 512 + c) * 8 + h) * 8 + w]);
}

// Weight transposes fused:
//   w1-w3: fp32 [CO][CI][3][3] -> bf16 [9][CO][CI]  (LDS-staged path)
//   w4,w5: fp32 [64][64][3][3] -> bf16 PARITY-SUMMED 2x2 effective taps, packed
//          16x16x32 B-fragment order [cls][tap2][nt][ch][lane][8]  (65536 elems each)
//          cls=py*2+px (output parity), tap2=i*2+j (2x2), co=nt*16+(lane&15),
//          ci=ch*32+(lane>>4)*8+e.  W_eff = sum over orig rows R(py,i) x cols C(px,j):
//          R(0,0)={0} R(0,1)={1,2} R(1,0)={0,1} R(1,1)={2}  (same for cols).
//          Exact: nearest-up2x + 3x3 conv == per-parity 2x2 conv with summed weights.
//   wf:    fp32 [3][64][3][3]  -> bf16 packed 16x16x32 [tap][ch][lane][8], co padded 3->16
__global__ void wtrans_all_kernel(const float* __restrict__ w1, __hip_bfloat16* __restrict__ o1,
                                  const float* __restrict__ w2, __hip_bfloat16* __restrict__ o2,
                                  const float* __restrict__ w3, __hip_bfloat16* __restrict__ o3,
                                  const float* __restrict__ w4, __hip_bfloat16* __restrict__ o4,
                                  const float* __restrict__ w5, __hip_bfloat16* __restrict__ o5,
                                  const float* __restrict__ wf, __hip_bfloat16* __restrict__ of) {
    int t = blockIdx.x * 256 + threadIdx.x;
    if (t >= 1688576) return;
    if (t < 1548288) {
        // [9][CO][CI] for stages 1-3
        const float* w; __hip_bfloat16* o; int lgci, lgco;
        if      (t < 1179648) { w = w1; o = o1; lgci = 9; lgco = 8; }
        else if (t < 1474560) { t -= 1179648; w = w2; o = o2; lgci = 8; lgco = 7; }
        else                  { t -= 1474560; w = w3; o = o3; lgci = 7; lgco = 6; }
        int CI = 1 << lgci;
        int ci = t & (CI - 1);
        int co = (t >> lgci) & ((1 << lgco) - 1);
        int tap = t >> (lgci + lgco);
        o[t] = __float2bfloat16(w[((size_t)co * CI + ci) * 9 + tap]);
    } else if (t < 1679360) {
        // parity-summed packed layout for stages 4/5
        int u = t - 1548288;
        const float* w; __hip_bfloat16* o;
        if (u < 65536) { w = w4; o = o4; }
        else           { u -= 65536; w = w5; o = o5; }
        int j   = u & 7;
        int ln  = (u >> 3) & 63;
        int ch  = (u >> 9) & 1;
        int nt  = (u >> 10) & 3;
        int tp  = (u >> 12) & 3;
        int cls = (u >> 14) & 3;
        int py = cls >> 1, px = cls & 1;
        int i = tp >> 1, jj = tp & 1;
        int co = nt * 16 + (ln & 15);
        int ci = ch * 32 + (ln >> 4) * 8 + j;
        int r0 = i * (1 + py), rc = py ? (2 - i) : (1 + i);
        int c0 = jj * (1 + px), cc = px ? (2 - jj) : (1 + jj);
        const float* wb = w + ((size_t)co * 64 + ci) * 9;
        float s = 0.f;
        for (int rr = 0; rr < rc; ++rr)
            for (int c2 = 0; c2 < cc; ++c2)
                s += wb[(r0 + rr) * 3 + (c0 + c2)];
        o[u] = __float2bfloat16(s);
    } else {
        // packed final-conv 16x16x32 layout (9216 elems), co padded 3->16
        int u = t - 1679360;
        int j  = u & 7;
        int ln = (u >> 3) & 63;
        int ch = (u >> 9) & 1;
        int tap = u >> 10;
        int rr = ln & 15, qq = ln >> 4;
        int ci = ch * 32 + qq * 8 + j;
        float v = (rr < 3) ? wf[((size_t)rr * 64 + ci) * 9 + tap] : 0.f;
        of[u] = __float2bfloat16(v);
    }
}

// All style FCs fused. S laid out contiguously: S1@0 (8x256), S2@2048 (8x128),
// S3@3072, S4@3584, S5@4096 (8x64 each). One wave per (stage,b,o) -> 4608 waves.
__global__ void style_all_kernel(const float* __restrict__ style,
                                 const float* __restrict__ fw1, const float* __restrict__ fb1,
                                 const float* __restrict__ fw2, const float* __restrict__ fb2,
                                 const float* __restrict__ fw3, const float* __restrict__ fb3,
                                 const float* __restrict__ fw4, const float* __restrict__ fb4,
                                 const float* __restrict__ fw5, const float* __restrict__ fb5,
                                 float* __restrict__ S) {
    int wvid = blockIdx.x * 4 + (threadIdx.x >> 6);
    int lane = threadIdx.x & 63;
    const float* fw; const float* fb; int lg, sOff, local;
    if      (wvid < 2048) { fw = fw1; fb = fb1; lg = 8; sOff = 0;    local = wvid; }
    else if (wvid < 3072) { fw = fw2; fb = fb2; lg = 7; sOff = 2048; local = wvid - 2048; }
    else if (wvid < 3584) { fw = fw3; fb = fb3; lg = 6; sOff = 3072; local = wvid - 3072; }
    else if (wvid < 4096) { fw = fw4; fb = fb4; lg = 6; sOff = 3584; local = wvid - 3584; }
    else                  { fw = fw5; fb = fb5; lg = 6; sOff = 4096; local = wvid - 4096; }
    int b = local >> lg, o = local & ((1 << lg) - 1);
    const float* sb = style + b * 512;
    const float* fwo = fw + (size_t)o * 512;
    float p = 0.f;
    #pragma unroll
    for (int k = lane; k < 512; k += 64) p += sb[k] * fwo[k];
    #pragma unroll
    for (int off = 32; off > 0; off >>= 1) p += __shfl_down(p, off);
    if (lane == 0) S[sOff + local] = p + fb[o];
}

// ---------------- K-split partial conv (stages 1-3, unchanged) ----------------
template <int CI, int CO, int HS, int WS>
__launch_bounds__(512)
__global__ void conv_partial_kernel(const __hip_bfloat16* __restrict__ actIn,
                                    const __hip_bfloat16* __restrict__ wtr,
                                    float* __restrict__ Part) {
    constexpr int HO = HS * 2, WO = WS * 2;
    constexpr size_t sliceN = (size_t)8 * HO * WO * CO;
    const int tid = threadIdx.x;
    const int lane = tid & 63, wv = tid >> 6;       // wv in [0,8)
    const int r = lane & 15, q = lane >> 4;
    const int pw = WO / 16, ppb = (HO / 16) * pw;
    const int b = blockIdx.x / ppb;
    const int prest = blockIdx.x - b * ppb;
    const int ph = prest / pw, pwi = prest - ph * pw;
    const int oh0 = ph * 16, ow0 = pwi * 16;
    const int sh0 = oh0 >> 1, sw0 = ow0 >> 1;
    const int n0 = blockIdx.y * 64;
    const int ciOff = blockIdx.z * 64;

    __shared__ alignas(16) __hip_bfloat16 Tile[100 * 72];
    __shared__ alignas(16) __hip_bfloat16 Wlds[2][64 * 72];

    f32x4 acc[2][4];
    #pragma unroll
    for (int i = 0; i < 2; ++i)
        #pragma unroll
        for (int j = 0; j < 4; ++j) acc[i][j] = f32x4{0.f, 0.f, 0.f, 0.f};

    for (int i = tid; i < 800; i += 512) {
        int pix = i >> 3, koct = i & 7;
        int tr = pix / 10, tc2 = pix - tr * 10;
        int su = sh0 - 1 + tr, sv = sw0 - 1 + tc2;
        uint4 v = {0, 0, 0, 0};
        if (su >= 0 && su < HS && sv >= 0 && sv < WS)
            v = *(const uint4*)(actIn + ((size_t)((b * HS + su) * WS + sv) * CI + ciOff + koct * 8));
        *(uint4*)&Tile[pix * 72 + koct * 8] = v;
    }
    {
        int co = tid >> 3, koct = tid & 7;
        *(uint4*)&Wlds[0][co * 72 + koct * 8] =
            *(const uint4*)(wtr + ((size_t)(n0 + co)) * CI + ciOff + koct * 8);
    }
    __syncthreads();

    #pragma unroll 1
    for (int tap = 0; tap < 9; ++tap) {
        const bool pf = (tap < 8);
        uint4 wr0 = {0,0,0,0};
        if (pf) {
            int co0 = tid >> 3, k0 = tid & 7;
            wr0 = *(const uint4*)(wtr + ((size_t)(tap + 1) * CO + n0 + co0) * CI + ciOff + k0 * 8);
        }
        const int dyv = tap / 3;
        const int dxm1 = tap - dyv * 3 - 1;
        const int tc = ((r + dxm1) >> 1) + 1;
        int apix[2];
        #pragma unroll
        for (int mt = 0; mt < 2; ++mt)
            apix[mt] = ((((wv * 2 + mt) + dyv - 1) >> 1) + 1) * 10 + tc;

        const int buf = tap & 1;
        #pragma unroll
        for (int ch = 0; ch < 2; ++ch) {
            bf16x8 af[2], bfr[4];
            #pragma unroll
            for (int mt = 0; mt < 2; ++mt)
                af[mt] = *(const bf16x8*)&Tile[apix[mt] * 72 + ch * 32 + q * 8];
            #pragma unroll
            for (int nt = 0; nt < 4; ++nt)
                bfr[nt] = *(const bf16x8*)&Wlds[buf][(nt * 16 + r) * 72 + ch * 32 + q * 8];
            #pragma unroll
            for (int mt = 0; mt < 2; ++mt)
                #pragma unroll
                for (int nt = 0; nt < 4; ++nt)
                    acc[mt][nt] = __builtin_amdgcn_mfma_f32_16x16x32_bf16(
                        af[mt], bfr[nt], acc[mt][nt], 0, 0, 0);
        }
        if (pf) {
            int nb = buf ^ 1;
            int co0 = tid >> 3, k0 = tid & 7;
            *(uint4*)&Wlds[nb][co0 * 72 + k0 * 8] = wr0;
            __syncthreads();
        }
    }

    float* P = Part + (size_t)blockIdx.z * sliceN;
    #pragma unroll
    for (int mt = 0; mt < 2; ++mt) {
        const int prow = wv * 2 + mt;
        #pragma unroll
        for (int t2 = 0; t2 < 4; ++t2) {
            const int pcol = q * 4 + t2;
            const size_t obase = ((size_t)(b * HO + oh0 + prow) * WO + ow0 + pcol) * CO + n0;
            #pragma unroll
            for (int nt = 0; nt < 4; ++nt)
                P[obase + nt * 16 + r] = acc[mt][nt][t2];
        }
    }
}

// sum KS fp32 partial slices -> scale + relu -> bf16 NHWC
template <int KS, int CO, int HW>
__launch_bounds__(256)
__global__ void reduce_kernel(const float* __restrict__ Part, const float* __restrict__ S,
                              __hip_bfloat16* __restrict__ actOut) {
    constexpr size_t sliceN = (size_t)8 * HW * CO;
    size_t e = ((size_t)blockIdx.x * 256 + threadIdx.x) * 4;
    if (e >= sliceN) return;
    f32x4 sum = {0.f, 0.f, 0.f, 0.f};
    #pragma unroll
    for (int k = 0; k < KS; ++k) sum += *(const f32x4*)(Part + (size_t)k * sliceN + e);
    const int co = (int)(e & (CO - 1));
    const int b = (int)(e / ((size_t)HW * CO));
    const float* Sb = S + b * CO + co;
    union { ushort4 u; __hip_bfloat16 h[4]; } pack;
    #pragma unroll
    for (int j = 0; j < 4; ++j)
        pack.h[j] = __float2bfloat16(fmaxf(sum[j] * Sb[j], 0.f));
    *(ushort4*)((unsigned short*)actOut + e) = pack.u;
}

// ---------------- fused conv, stages 4-5: parity-decomposed 2x2 taps ----------------
// up2x+3x3 == 4 parity classes of 2x2 conv with pre-summed weights (exact identity).
// One wave per parity class; each wave computes its 8x8 subgrid of the 16x16 patch
// x 64 co with 4 taps x 4 m-tiles x 4 nt x 2 ch = 128 MFMA (vs 288 for 9-tap form).
// A-tile (10x10 x 64ci) staged to LDS once; B-fragments direct from global
// (L2-resident 128 KB table), register double-buffered; no barriers in the tap loop.
template <int HS, int WS>
__launch_bounds__(256)
__global__ void conv_patch_kernel(const __hip_bfloat16* __restrict__ actIn,
                                  const __hip_bfloat16* __restrict__ wpk,
                                  const float* __restrict__ S,
                                  __hip_bfloat16* __restrict__ actOut) {
    constexpr int HO = HS * 2, WO = WS * 2;

    const int tid = threadIdx.x;
    const int lane = tid & 63, wv = tid >> 6;        // wv = parity class
    const int r = lane & 15, q = lane >> 4;
    const int rs = r >> 3, sc = r & 7;               // m = rs*8+sc: row-pair sel, subgrid col
    const int lane8 = lane * 8;
    const int py = wv >> 1, px = wv & 1;

    const int pw = WO / 16, ppb = (HO / 16) * pw;
    const int b = blockIdx.x / ppb;
    const int prest = blockIdx.x - b * ppb;
    const int ph = prest / pw, pwi = prest - ph * pw;
    const int oh0 = ph * 16, ow0 = pwi * 16;
    const int sh0 = oh0 >> 1, sw0 = ow0 >> 1;

    __shared__ alignas(16) __hip_bfloat16 Tile[100 * 72];

    f32x4 acc[4][4];                                 // [mt][nt]
    #pragma unroll
    for (int i = 0; i < 4; ++i)
        #pragma unroll
        for (int j = 0; j < 4; ++j) acc[i][j] = f32x4{0.f, 0.f, 0.f, 0.f};

    // stage source tile once (10x10 px x 64 ci, padded stride 72)
    for (int i = tid; i < 800; i += 256) {
        int pix = i >> 3, koct = i & 7;
        int tr = pix / 10, tc2 = pix - tr * 10;
        int su = sh0 - 1 + tr, sv = sw0 - 1 + tc2;
        uint4 v = {0, 0, 0, 0};
        if (su >= 0 && su < HS && sv >= 0 && sv < WS)
            v = *(const uint4*)(actIn + ((size_t)((b * HS + su) * WS + sv) * 64 + koct * 8));
        *(uint4*)&Tile[pix * 72 + koct * 8] = v;
    }
    __syncthreads();

    // per-class weight table base: 4tap x 4nt x 2ch x 512 = 16384 elems per class
    const __hip_bfloat16* wcls = wpk + ((size_t)wv << 14);

    bf16x8 bA[4][2], bB[4][2];                       // [nt][ch]

    auto loadB = [&](bf16x8 (&dst)[4][2], int tp) {
        #pragma unroll
        for (int nt = 0; nt < 4; ++nt)
            #pragma unroll
            for (int ch = 0; ch < 2; ++ch)
                dst[nt][ch] = *(const bf16x8*)(wcls + (tp << 12) + ((nt * 2 + ch) << 9) + lane8);
    };

    auto compute = [&](int tp, bf16x8 (&bfr)[4][2]) {
        const int i = tp >> 1, j = tp & 1;
        const int ro = i + py, co2 = j + px;
        int apix[4];
        #pragma unroll
        for (int mt = 0; mt < 4; ++mt)
            apix[mt] = (2 * mt + rs + ro) * 10 + (sc + co2);
        #pragma unroll
        for (int ch = 0; ch < 2; ++ch) {
            bf16x8 af[4];
            #pragma unroll
            for (int mt = 0; mt < 4; ++mt)
                af[mt] = *(const bf16x8*)&Tile[apix[mt] * 72 + ch * 32 + q * 8];
            #pragma unroll
            for (int mt = 0; mt < 4; ++mt)
                #pragma unroll
                for (int nt = 0; nt < 4; ++nt)
                    acc[mt][nt] = __builtin_amdgcn_mfma_f32_16x16x32_bf16(
                        af[mt], bfr[nt][ch], acc[mt][nt], 0, 0, 0);
        }
    };

    loadB(bA, 0);
    loadB(bB, 1);
    compute(0, bA);
    loadB(bA, 2);
    compute(1, bB);
    loadB(bB, 3);
    compute(2, bA);
    compute(3, bB);

    float sv_[4];
    #pragma unroll
    for (int nt = 0; nt < 4; ++nt) sv_[nt] = S[b * 64 + nt * 16 + r];
    #pragma unroll
    for (int mt = 0; mt < 4; ++mt) {
        #pragma unroll
        for (int t2 = 0; t2 < 4; ++t2) {
            const int m = q * 4 + t2;
            const int row = oh0 + 4 * mt + 2 * (m >> 3) + py;
            const int col = ow0 + 2 * (m & 7) + px;
            const size_t obase = ((size_t)(b * HO + row) * WO + col) * 64;
            #pragma unroll
            for (int nt = 0; nt < 4; ++nt)
                actOut[obase + nt * 16 + r] =
                    __float2bfloat16(fmaxf(acc[mt][nt][t2] * sv_[nt], 0.f));
        }
    }
}

// ---------------- final conv: 64->3 at 256x256, +bias, fp32 NCHW out ----------------
__launch_bounds__(256)
__global__ void conv_final_kernel(const __hip_bfloat16* __restrict__ actIn, // [8][256][256][64]
                                  const __hip_bfloat16* __restrict__ wpkF, // packed [9][2][64][8]
                                  const float* __restrict__ bias,
                                  float* __restrict__ out) {               // [8][3][256][256]
    constexpr int HO = 256, WO = 256;
    const int tid = threadIdx.x, lane = tid & 63, wv = tid >> 6;
    const int r = lane & 15, q = lane >> 4;
    const int lane8 = lane * 8;

    const int ppb = 32 * 16;
    const int b = blockIdx.x / ppb;
    const int prest = blockIdx.x - b * ppb;
    const int ph = prest >> 4, pwi = prest & 15;
    const int oh0 = ph * 8, ow0 = pwi * 16;

    __shared__ alignas(16) __hip_bfloat16 Tile[10 * 18 * 72];

    for (int i = tid; i < 1440; i += 256) {
        int pix = i >> 3, koct = i & 7;
        int tr = pix / 18, tc2 = pix - tr * 18;
        int u = oh0 - 1 + tr, v = ow0 - 1 + tc2;
        uint4 val = {0, 0, 0, 0};
        if (u >= 0 && u < HO && v >= 0 && v < WO)
            val = *(const uint4*)(actIn + ((size_t)((b * HO + u) * WO + v) * 64 + koct * 8));
        *(uint4*)&Tile[pix * 72 + koct * 8] = val;
    }
    __syncthreads();

    f32x4 acc[2];
    acc[0] = f32x4{0.f, 0.f, 0.f, 0.f};
    acc[1] = f32x4{0.f, 0.f, 0.f, 0.f};

    #pragma unroll 1
    for (int tap = 0; tap < 9; ++tap) {
        const int dyv = tap / 3;
        const int dxv = tap - dyv * 3;
        const int tc = r + dxv;
        int apix[2];
        #pragma unroll
        for (int mt = 0; mt < 2; ++mt)
            apix[mt] = (wv * 2 + mt + dyv) * 18 + tc;
        #pragma unroll
        for (int ch = 0; ch < 2; ++ch) {
            bf16x8 bfr = *(const bf16x8*)(wpkF + ((tap * 2 + ch) << 9) + lane8);
            #pragma unroll
            for (int mt = 0; mt < 2; ++mt) {
                bf16x8 af = *(const bf16x8*)&Tile[apix[mt] * 72 + ch * 32 + q * 8];
                acc[mt] = __builtin_amdgcn_mfma_f32_16x16x32_bf16(af, bfr, acc[mt], 0, 0, 0);
            }
        }
    }

    if (r < 3) {
        const float bs = bias[r];
        #pragma unroll
        for (int mt = 0; mt < 2; ++mt) {
            const int prow = wv * 2 + mt;
            #pragma unroll
            for (int t2 = 0; t2 < 4; ++t2) {
                const int pcol = q * 4 + t2;
                out[((size_t)(b * 3 + r) << 16) + (oh0 + prow) * 256 + ow0 + pcol] =
                    acc[mt][t2] + bs;
            }
        }
    }
}

// ---------------- launch ----------------
extern "C" void kernel_launch(void* const* d_in, const int* in_sizes, int n_in,
                              void* d_out, int out_size, void* d_ws, size_t ws_size,
                              hipStream_t stream) {
    const float* x    = (const float*)d_in[0];
    const float* sty  = (const float*)d_in[1];
    const float* w1   = (const float*)d_in[2];
    const float* fw1  = (const float*)d_in[3];
    const float* fb1  = (const float*)d_in[4];
    const float* w2   = (const float*)d_in[5];
    const float* fw2  = (const float*)d_in[6];
    const float* fb2  = (const float*)d_in[7];
    const float* w3   = (const float*)d_in[8];
    const float* fw3  = (const float*)d_in[9];
    const float* fb3  = (const float*)d_in[10];
    const float* w4   = (const float*)d_in[11];
    const float* fw4  = (const float*)d_in[12];
    const float* fb4  = (const float*)d_in[13];
    const float* w5   = (const float*)d_in[14];
    const float* fw5  = (const float*)d_in[15];
    const float* fb5  = (const float*)d_in[16];
    const float* wf   = (const float*)d_in[17];
    const float* bf   = (const float*)d_in[18];
    float* out = (float*)d_out;

    char* ws = (char*)d_ws;
    size_t off = 0;
    auto alloc = [&](size_t bytes) {
        char* p = ws + off;
        off += (bytes + 255) & ~(size_t)255;
        return p;
    };
    float* S1 = (float*)alloc(8 * 256 * 4);
    float* S2 = (float*)alloc(8 * 128 * 4);
    float* S3 = (float*)alloc(8 * 64 * 4);
    float* S4 = (float*)alloc(8 * 64 * 4);
    float* S5 = (float*)alloc(8 * 64 * 4);
    __hip_bfloat16* act0 = (__hip_bfloat16*)alloc((size_t)262144 * 2);   // 8x8x8x512
    __hip_bfloat16* act1 = (__hip_bfloat16*)alloc((size_t)524288 * 2);   // 8x16x16x256
    __hip_bfloat16* act2 = (__hip_bfloat16*)alloc((size_t)1048576 * 2);  // 8x32x32x128
    __hip_bfloat16* act3 = (__hip_bfloat16*)alloc((size_t)2097152 * 2);  // 8x64x64x64
    __hip_bfloat16* act4 = (__hip_bfloat16*)alloc((size_t)8388608 * 2);  // 8x128x128x64
    __hip_bfloat16* act5 = (__hip_bfloat16*)alloc((size_t)33554432 * 2); // 8x256x256x64
    __hip_bfloat16* wt1  = (__hip_bfloat16*)alloc((size_t)9 * 256 * 512 * 2);
    __hip_bfloat16* wt2  = (__hip_bfloat16*)alloc((size_t)9 * 128 * 256 * 2);
    __hip_bfloat16* wt3  = (__hip_bfloat16*)alloc((size_t)9 * 64 * 128 * 2);
    __hip_bfloat16* wt4  = (__hip_bfloat16*)alloc((size_t)65536 * 2);    // parity-packed
    __hip_bfloat16* wt5  = (__hip_bfloat16*)alloc((size_t)65536 * 2);    // parity-packed
    __hip_bfloat16* wtF  = (__hip_bfloat16*)alloc((size_t)9 * 16 * 64 * 2); // packed 16x16
    if (off > ws_size) return;

    // fp32 K-split partial scratch (16 MB) aliased onto act5 (64 MB, written only by
    // stage 5 which runs after the last reduce) -- no extra ws footprint.
    float* Part = (float*)act5;

    convert_x_kernel<<<1024, 256, 0, stream>>>(x, act0);
    wtrans_all_kernel<<<6596, 256, 0, stream>>>(w1, wt1, w2, wt2, w3, wt3,
                                                w4, wt4, w5, wt5, wf, wtF);
    style_all_kernel<<<1152, 256, 0, stream>>>(sty, fw1, fb1, fw2, fb2, fw3, fb3,
                                               fw4, fb4, fw5, fb5, S1);

    // stages 1-3: K-split partials + reduce
    conv_partial_kernel<512, 256, 8, 8><<<dim3(8, 4, 8), 512, 0, stream>>>(act0, wt1, Part);
    reduce_kernel<8, 256, 256><<<512, 256, 0, stream>>>(Part, S1, act1);
    conv_partial_kernel<256, 128, 16, 16><<<dim3(32, 2, 4), 512, 0, stream>>>(act1, wt2, Part);
    reduce_kernel<4, 128, 1024><<<1024, 256, 0, stream>>>(Part, S2, act2);
    conv_partial_kernel<128, 64, 32, 32><<<dim3(128, 1, 2), 512, 0, stream>>>(act2, wt3, Part);
    reduce_kernel<2, 64, 4096><<<2048, 256, 0, stream>>>(Part, S3, act3);

    // stages 4-5: parity-decomposed 2x2-tap fused conv (2.25x fewer MFMA)
    conv_patch_kernel<64, 64><<<dim3(512), 256, 0, stream>>>(act3, wt4, S4, act4);
    conv_patch_kernel<128, 128><<<dim3(2048), 256, 0, stream>>>(act4, wt5, S5, act5);
    conv_final_kernel<<<4096, 256, 0, stream>>>(act5, wtF, bf, out);
}